// Round 1
// baseline (909.566 us; speedup 1.0000x reference)
//
#include <hip/hip_runtime.h>
#include <math.h>

#define BATCH 4
#define NPTS 4096
#define KNBR 16
#define HDIM 128

__device__ __forceinline__ float gelu_f(float x) {
    return 0.5f * x * (1.0f + erff(x * 0.7071067811865476f));
}

__device__ __forceinline__ unsigned long long umin64(unsigned long long a, unsigned long long b) {
    return a < b ? a : b;
}

// ---------------- KNN: one block (256 thr) per query point ----------------
__global__ __launch_bounds__(256) void knn_kernel(const float* __restrict__ pts,
                                                  int* __restrict__ idx_out) {
    const int bid = blockIdx.x;
    const int b = bid >> 12;            // / 4096
    const int n = bid & (NPTS - 1);
    const int t = threadIdx.x;
    const float* __restrict__ base = pts + (size_t)b * NPTS * 6;

    const float qx = base[(size_t)n * 6 + 0];
    const float qy = base[(size_t)n * 6 + 1];
    const float qz = base[(size_t)n * 6 + 2];
    const float sqn = qx * qx + qy * qy + qz * qz;

    unsigned long long keys[16];
#pragma unroll
    for (int j = 0; j < 16; ++j) {
        const int m = t + 256 * j;
        const float cx = base[(size_t)m * 6 + 0];
        const float cy = base[(size_t)m * 6 + 1];
        const float cz = base[(size_t)m * 6 + 2];
        const float sqm = cx * cx + cy * cy + cz * cz;
        const float dot = qx * cx + qy * cy + qz * cz;
        float d2 = (sqn + sqm) - 2.0f * dot;   // same formula as reference
        d2 = fmaxf(d2, 0.0f);
        unsigned long long key =
            ((unsigned long long)__float_as_uint(d2) << 32) | (unsigned int)m;
        if (m == n) key = ~0ull;               // exclude self
        keys[j] = key;
    }
    unsigned long long lmin = keys[0];
#pragma unroll
    for (int j = 1; j < 16; ++j) lmin = umin64(lmin, keys[j]);

    __shared__ unsigned long long wmin[4];
    const int lane = t & 63;
    const int w = t >> 6;
    int* __restrict__ outp = idx_out + ((size_t)b * NPTS + n) * KNBR;

    for (int r = 0; r < KNBR; ++r) {
        unsigned long long v = lmin;
#pragma unroll
        for (int s = 32; s >= 1; s >>= 1) {
            unsigned long long o = __shfl_xor(v, s, 64);
            v = umin64(v, o);
        }
        if (lane == 0) wmin[w] = v;
        __syncthreads();
        const unsigned long long g =
            umin64(umin64(wmin[0], wmin[1]), umin64(wmin[2], wmin[3]));
        if (t == 0) outp[r] = (int)(g & 0xffffffffull);
        if (lmin == g) {  // unique owner (key embeds m)
#pragma unroll
            for (int j = 0; j < 16; ++j)
                if (keys[j] == g) keys[j] = ~0ull;
            unsigned long long nm = keys[0];
#pragma unroll
            for (int j = 1; j < 16; ++j) nm = umin64(nm, keys[j]);
            lmin = nm;
        }
        __syncthreads();
    }
}

// ---------------- fused MLP: one block per 8 points ----------------
__device__ __forceinline__ void layer2_max_half(
    const float (* __restrict__ h1)[HDIM], const float* __restrict__ W,
    const float* __restrict__ bias, float (* __restrict__ outf)[HDIM],
    int half, int t)
{
    const int col = t & 127;
    const int pb = t >> 7;
    for (int pp = 0; pp < 2; ++pp) {
        const int pl = pp * 2 + pb;     // 0..3 local point within half
        const int p = half * 4 + pl;
        float acc[16];
#pragma unroll
        for (int j = 0; j < 16; ++j) acc[j] = 0.0f;
        for (int kk = 0; kk < HDIM; kk += 4) {
            const float w0 = W[(size_t)(kk + 0) * HDIM + col];
            const float w1 = W[(size_t)(kk + 1) * HDIM + col];
            const float w2 = W[(size_t)(kk + 2) * HDIM + col];
            const float w3 = W[(size_t)(kk + 3) * HDIM + col];
#pragma unroll
            for (int j = 0; j < 16; ++j) {
                const float4 hv = *(const float4*)(&h1[pl * 16 + j][kk]);
                acc[j] = fmaf(hv.x, w0, acc[j]);
                acc[j] = fmaf(hv.y, w1, acc[j]);
                acc[j] = fmaf(hv.z, w2, acc[j]);
                acc[j] = fmaf(hv.w, w3, acc[j]);
            }
        }
        float mx = acc[0];
#pragma unroll
        for (int j = 1; j < 16; ++j) mx = fmaxf(mx, acc[j]);
        outf[p][col] = mx + bias[col];
    }
}

__global__ __launch_bounds__(256) void mlp_kernel(
    const float* __restrict__ pts, const int* __restrict__ knn_idx,
    const float* __restrict__ Wc1, const float* __restrict__ bc1,
    const float* __restrict__ Wc2, const float* __restrict__ bc2,
    const float* __restrict__ Wn1, const float* __restrict__ bn1,
    const float* __restrict__ Wn2, const float* __restrict__ bn2,
    const float* __restrict__ Wo1, const float* __restrict__ bo1,
    const float* __restrict__ Wo2, const float* __restrict__ bo2,
    float* __restrict__ outp)
{
    __shared__ float rel[128][3];
    __shared__ float nin4[128][4];
    __shared__ float h1[64][HDIM];      // 32 KB, reused per half & per branch
    __shared__ float cf[8][HDIM];
    __shared__ float nf[8][HDIM];
    __shared__ float o1s[8][HDIM];
    __shared__ float qpt[8][6];

    const int t = threadIdx.x;
    const int blk = blockIdx.x;
    const int b = blk >> 9;             // 512 blocks per batch
    const int n0 = (blk & 511) * 8;
    const float* __restrict__ base = pts + (size_t)b * NPTS * 6;

    if (t < 48) {
        qpt[t / 6][t % 6] = base[(size_t)(n0 + t / 6) * 6 + (t % 6)];
    }
    __syncthreads();
    if (t < 128) {
        const int p = t >> 4;
        const int m = knn_idx[((size_t)b * NPTS + n0 + p) * KNBR + (t & 15)];
        const float cx = base[(size_t)m * 6 + 0];
        const float cy = base[(size_t)m * 6 + 1];
        const float cz = base[(size_t)m * 6 + 2];
        const float nx = base[(size_t)m * 6 + 3];
        const float ny = base[(size_t)m * 6 + 4];
        const float nz = base[(size_t)m * 6 + 5];
        rel[t][0] = cx - qpt[p][0];
        rel[t][1] = cy - qpt[p][1];
        rel[t][2] = cz - qpt[p][2];
        nin4[t][0] = nx; nin4[t][1] = ny; nin4[t][2] = nz;
        nin4[t][3] = 1.0f - (qpt[p][3] * nx + qpt[p][4] * ny + qpt[p][5] * nz);
    }
    __syncthreads();

    // ---- coord branch ----
    {
        const int col = t & 127;
        const float w0 = Wc1[col], w1 = Wc1[HDIM + col], w2 = Wc1[2 * HDIM + col];
        const float bb = bc1[col];
        for (int half = 0; half < 2; ++half) {
#pragma unroll
            for (int rep = 0; rep < 32; ++rep) {
                const int rl = rep * 2 + (t >> 7);
                const int row = half * 64 + rl;
                const float v = bb + rel[row][0] * w0 + rel[row][1] * w1 + rel[row][2] * w2;
                h1[rl][col] = gelu_f(v);
            }
            __syncthreads();
            layer2_max_half(h1, Wc2, bc2, cf, half, t);
            __syncthreads();
        }
    }
    // ---- normal branch ----
    {
        const int col = t & 127;
        const float w0 = Wn1[col], w1 = Wn1[HDIM + col];
        const float w2 = Wn1[2 * HDIM + col], w3 = Wn1[3 * HDIM + col];
        const float bb = bn1[col];
        for (int half = 0; half < 2; ++half) {
#pragma unroll
            for (int rep = 0; rep < 32; ++rep) {
                const int rl = rep * 2 + (t >> 7);
                const int row = half * 64 + rl;
                const float v = bb + nin4[row][0] * w0 + nin4[row][1] * w1 +
                                nin4[row][2] * w2 + nin4[row][3] * w3;
                h1[rl][col] = gelu_f(v);
            }
            __syncthreads();
            layer2_max_half(h1, Wn2, bn2, nf, half, t);
            __syncthreads();
        }
    }
    // ---- output MLP layer 1 ----
    {
        const int col = t & 127;
        const int pb = t >> 7;
        for (int pp = 0; pp < 4; ++pp) {
            const int p = pp * 2 + pb;
            float acc = bo1[col];
            for (int k2 = 0; k2 < HDIM; k2 += 4) {
                const float4 cv = *(const float4*)(&cf[p][k2]);
                acc = fmaf(cv.x, Wo1[(size_t)(k2 + 0) * HDIM + col], acc);
                acc = fmaf(cv.y, Wo1[(size_t)(k2 + 1) * HDIM + col], acc);
                acc = fmaf(cv.z, Wo1[(size_t)(k2 + 2) * HDIM + col], acc);
                acc = fmaf(cv.w, Wo1[(size_t)(k2 + 3) * HDIM + col], acc);
            }
            for (int k2 = 0; k2 < HDIM; k2 += 4) {
                const float4 nv = *(const float4*)(&nf[p][k2]);
                acc = fmaf(nv.x, Wo1[(size_t)(HDIM + k2 + 0) * HDIM + col], acc);
                acc = fmaf(nv.y, Wo1[(size_t)(HDIM + k2 + 1) * HDIM + col], acc);
                acc = fmaf(nv.z, Wo1[(size_t)(HDIM + k2 + 2) * HDIM + col], acc);
                acc = fmaf(nv.w, Wo1[(size_t)(HDIM + k2 + 3) * HDIM + col], acc);
            }
            o1s[p][col] = gelu_f(acc);
        }
    }
    __syncthreads();
    // ---- output MLP layer 2 ----
    {
        const int col = t & 127;
        const int pb = t >> 7;
        for (int pp = 0; pp < 4; ++pp) {
            const int p = pp * 2 + pb;
            float acc = bo2[col];
            for (int k2 = 0; k2 < HDIM; k2 += 4) {
                const float4 ov = *(const float4*)(&o1s[p][k2]);
                acc = fmaf(ov.x, Wo2[(size_t)(k2 + 0) * HDIM + col], acc);
                acc = fmaf(ov.y, Wo2[(size_t)(k2 + 1) * HDIM + col], acc);
                acc = fmaf(ov.z, Wo2[(size_t)(k2 + 2) * HDIM + col], acc);
                acc = fmaf(ov.w, Wo2[(size_t)(k2 + 3) * HDIM + col], acc);
            }
            outp[((size_t)b * NPTS + n0 + p) * HDIM + col] = acc;
        }
    }
}

extern "C" void kernel_launch(void* const* d_in, const int* in_sizes, int n_in,
                              void* d_out, int out_size, void* d_ws, size_t ws_size,
                              hipStream_t stream) {
    const float* pts = (const float*)d_in[0];
    const float* Wc1 = (const float*)d_in[1];
    const float* bc1 = (const float*)d_in[2];
    const float* Wc2 = (const float*)d_in[3];
    const float* bc2 = (const float*)d_in[4];
    const float* Wn1 = (const float*)d_in[5];
    const float* bn1 = (const float*)d_in[6];
    const float* Wn2 = (const float*)d_in[7];
    const float* bn2 = (const float*)d_in[8];
    const float* Wo1 = (const float*)d_in[9];
    const float* bo1 = (const float*)d_in[10];
    const float* Wo2 = (const float*)d_in[11];
    const float* bo2 = (const float*)d_in[12];
    float* outp = (float*)d_out;
    int* idx = (int*)d_ws;   // BATCH*NPTS*KNBR ints = 1 MB

    knn_kernel<<<dim3(BATCH * NPTS), dim3(256), 0, stream>>>(pts, idx);
    mlp_kernel<<<dim3(BATCH * NPTS / 8), dim3(256), 0, stream>>>(
        pts, idx, Wc1, bc1, Wc2, bc2, Wn1, bn1, Wn2, bn2, Wo1, bo1, Wo2, bo2, outp);
}

// Round 2
// 391.437 us; speedup vs baseline: 2.3237x; 2.3237x over previous
//
#include <hip/hip_runtime.h>
#include <math.h>

#define BATCH 4
#define NPTS 4096
#define KNBR 16
#define HDIM 128

typedef __attribute__((ext_vector_type(8))) short bf16x8;
typedef __attribute__((ext_vector_type(4))) float f32x4;

// ws layout: [0, 1MB): knn idx (int). [1MB, +320KB): split weights (ushort)
#define WSOFF_W (1u << 20)
#define WC_HI 0
#define WC_LO 16384
#define WN_HI 32768
#define WN_LO 49152
#define WO1_HI 65536
#define WO1_LO 98304
#define WO2_HI 131072
#define WO2_LO 147456

__device__ __forceinline__ float gelu_f(float x) {
    return 0.5f * x * (1.0f + erff(x * 0.7071067811865476f));
}

__device__ __forceinline__ unsigned long long umin64(unsigned long long a, unsigned long long b) {
    return a < b ? a : b;
}

__device__ __forceinline__ void bsplit(float x, short& hi, short& lo) {
    const unsigned u = __float_as_uint(x);
    hi = (short)(u >> 16);
    const float r = x - __uint_as_float(u & 0xffff0000u);
    lo = (short)(__float_as_uint(r) >> 16);
}

// ---------------- weight transpose + hi/lo split ----------------
__global__ __launch_bounds__(256) void prep_weights(
    const float* __restrict__ Wc2, const float* __restrict__ Wn2,
    const float* __restrict__ Wo1, const float* __restrict__ Wo2,
    unsigned short* __restrict__ wbuf)
{
    const int e = blockIdx.x * 256 + threadIdx.x;   // 0..81919
    const float* src;
    unsigned short *dh, *dl;
    int klog, idx;
    if (e < 16384)      { src = Wc2; dh = wbuf + WC_HI;  dl = wbuf + WC_LO;  klog = 7; idx = e; }
    else if (e < 32768) { src = Wn2; dh = wbuf + WN_HI;  dl = wbuf + WN_LO;  klog = 7; idx = e - 16384; }
    else if (e < 65536) { src = Wo1; dh = wbuf + WO1_HI; dl = wbuf + WO1_LO; klog = 8; idx = e - 32768; }
    else                { src = Wo2; dh = wbuf + WO2_HI; dl = wbuf + WO2_LO; klog = 7; idx = e - 65536; }
    const int n = idx >> klog;
    const int k = idx & ((1 << klog) - 1);
    const float x = src[(k << 7) + n];         // src is [K][128] row-major
    short hi, lo;
    bsplit(x, hi, lo);
    dh[idx] = (unsigned short)hi;
    dl[idx] = (unsigned short)lo;
}

// ---------------- KNN: one block (256 thr) per query point ----------------
__global__ __launch_bounds__(256) void knn_kernel(const float* __restrict__ pts,
                                                  int* __restrict__ idx_out) {
    const int bid = blockIdx.x;
    const int b = bid >> 12;
    const int n = bid & (NPTS - 1);
    const int t = threadIdx.x;
    const float* __restrict__ base = pts + (size_t)b * NPTS * 6;

    const float qx = base[(size_t)n * 6 + 0];
    const float qy = base[(size_t)n * 6 + 1];
    const float qz = base[(size_t)n * 6 + 2];
    const float sqn = qx * qx + qy * qy + qz * qz;

    unsigned long long keys[16];
#pragma unroll
    for (int j = 0; j < 16; ++j) {
        const int m = t + 256 * j;
        const float cx = base[(size_t)m * 6 + 0];
        const float cy = base[(size_t)m * 6 + 1];
        const float cz = base[(size_t)m * 6 + 2];
        const float sqm = cx * cx + cy * cy + cz * cz;
        const float dot = qx * cx + qy * cy + qz * cz;
        float d2 = (sqn + sqm) - 2.0f * dot;
        d2 = fmaxf(d2, 0.0f);
        unsigned long long key =
            ((unsigned long long)__float_as_uint(d2) << 32) | (unsigned int)m;
        if (m == n) key = ~0ull;
        keys[j] = key;
    }
    unsigned long long lmin = keys[0];
#pragma unroll
    for (int j = 1; j < 16; ++j) lmin = umin64(lmin, keys[j]);

    __shared__ unsigned long long wmin[4];
    const int lane = t & 63;
    const int w = t >> 6;
    int* __restrict__ outp = idx_out + ((size_t)b * NPTS + n) * KNBR;

    for (int r = 0; r < KNBR; ++r) {
        unsigned long long v = lmin;
#pragma unroll
        for (int s = 32; s >= 1; s >>= 1) {
            unsigned long long o = __shfl_xor(v, s, 64);
            v = umin64(v, o);
        }
        if (lane == 0) wmin[w] = v;
        __syncthreads();
        const unsigned long long g =
            umin64(umin64(wmin[0], wmin[1]), umin64(wmin[2], wmin[3]));
        if (t == 0) outp[r] = (int)(g & 0xffffffffull);
        if (lmin == g) {
#pragma unroll
            for (int j = 0; j < 16; ++j)
                if (keys[j] == g) keys[j] = ~0ull;
            unsigned long long nm = keys[0];
#pragma unroll
            for (int j = 1; j < 16; ++j) nm = umin64(nm, keys[j]);
            lmin = nm;
        }
        __syncthreads();
    }
}

// ---------------- branch compute: layer1 (VALU) + layer2 (MFMA) + k-max ----------------
template<int NIN>
__device__ __forceinline__ void branch_compute(
    const float (* __restrict__ inp)[4],           // 256 rows x 4 (LDS)
    const float* __restrict__ W1,                  // [NIN][128] fp32 global
    const float* __restrict__ b1,                  // [128]
    const float* __restrict__ b2,                  // [128]
    const unsigned short* __restrict__ w2hi,       // [128][128] bf16 (N-major)
    const unsigned short* __restrict__ w2lo,
    unsigned short (* __restrict__ catH)[264],
    unsigned short (* __restrict__ catL)[264],
    int colbase, int w, int l)
{
    const int lr = l & 15;
    const int lq = l >> 4;
    const int kb = lq * 8;

    f32x4 acc[2][8];
#pragma unroll
    for (int rt = 0; rt < 2; ++rt)
#pragma unroll
        for (int ct = 0; ct < 8; ++ct)
            acc[rt][ct] = (f32x4){0.f, 0.f, 0.f, 0.f};

    for (int ks = 0; ks < 4; ++ks) {
        const int c0 = ks * 32 + kb;
        // B fragments (issue loads early)
        bf16x8 bh[8], bl[8];
#pragma unroll
        for (int ct = 0; ct < 8; ++ct) {
            const unsigned short* wp = w2hi + (((lr + 16 * ct) << 7) + c0);
            const unsigned short* wq = w2lo + (((lr + 16 * ct) << 7) + c0);
            bh[ct] = *(const bf16x8*)wp;
            bl[ct] = *(const bf16x8*)wq;
        }
        // layer-1 weights/bias for this lane's 8 columns
        float wr[NIN][8], bb[8];
#pragma unroll
        for (int d = 0; d < NIN; ++d) {
            *(float4*)&wr[d][0] = *(const float4*)(W1 + (d << 7) + c0);
            *(float4*)&wr[d][4] = *(const float4*)(W1 + (d << 7) + c0 + 4);
        }
        *(float4*)&bb[0] = *(const float4*)(b1 + c0);
        *(float4*)&bb[4] = *(const float4*)(b1 + c0 + 4);

#pragma unroll
        for (int rt = 0; rt < 2; ++rt) {
            const int row = 32 * w + 16 * rt + lr;
            const float4 rv = *(const float4*)&inp[row][0];
            bf16x8 ah, al;
#pragma unroll
            for (int jj = 0; jj < 8; ++jj) {
                float x = bb[jj] + rv.x * wr[0][jj] + rv.y * wr[1][jj] + rv.z * wr[2][jj];
                if (NIN == 4) x += rv.w * wr[3][jj];
                x = gelu_f(x);
                short hi, lo;
                bsplit(x, hi, lo);
                ah[jj] = hi;
                al[jj] = lo;
            }
#pragma unroll
            for (int ct = 0; ct < 8; ++ct)
                acc[rt][ct] = __builtin_amdgcn_mfma_f32_16x16x32_bf16(ah, bh[ct], acc[rt][ct], 0, 0, 0);
#pragma unroll
            for (int ct = 0; ct < 8; ++ct)
                acc[rt][ct] = __builtin_amdgcn_mfma_f32_16x16x32_bf16(ah, bl[ct], acc[rt][ct], 0, 0, 0);
#pragma unroll
            for (int ct = 0; ct < 8; ++ct)
                acc[rt][ct] = __builtin_amdgcn_mfma_f32_16x16x32_bf16(al, bh[ct], acc[rt][ct], 0, 0, 0);
        }
    }
    // k-max over 16 neighbors (rows of each 16-row tile) + bias + split to cat
#pragma unroll
    for (int rt = 0; rt < 2; ++rt) {
        const int p = 2 * w + rt;
#pragma unroll
        for (int ct = 0; ct < 8; ++ct) {
            const f32x4 a = acc[rt][ct];
            float m = fmaxf(fmaxf(a[0], a[1]), fmaxf(a[2], a[3]));
            m = fmaxf(m, __shfl_xor(m, 16));
            m = fmaxf(m, __shfl_xor(m, 32));
            const int col = lr + 16 * ct;
            const float v = m + b2[col];
            if (lq == 0) {
                short hi, lo;
                bsplit(v, hi, lo);
                catH[p][colbase + col] = (unsigned short)hi;
                catL[p][colbase + col] = (unsigned short)lo;
            }
        }
    }
}

// ---------------- fused MLP with MFMA: one block (512 thr) per 16 points ----------------
__global__ __launch_bounds__(512, 1) void mlp_mfma(
    const float* __restrict__ pts, const int* __restrict__ knn_idx,
    const float* __restrict__ Wc1, const float* __restrict__ bc1,
    const float* __restrict__ bc2,
    const float* __restrict__ Wn1, const float* __restrict__ bn1,
    const float* __restrict__ bn2,
    const float* __restrict__ bo1, const float* __restrict__ bo2,
    const unsigned short* __restrict__ wbuf,
    float* __restrict__ outp)
{
    __shared__ float rel[256][4];
    __shared__ float nin[256][4];
    __shared__ float qpt[16][6];
    __shared__ unsigned short catH[16][264];   // stride 264 -> 2-way banks, free
    __shared__ unsigned short catL[16][264];
    __shared__ unsigned short o1H[16][136];
    __shared__ unsigned short o1L[16][136];

    const int t = threadIdx.x;
    const int w = t >> 6;
    const int l = t & 63;
    const int lr = l & 15;
    const int lq = l >> 4;
    const int kb = lq * 8;
    const int blk = blockIdx.x;
    const int b = blk >> 8;                 // 256 blocks per batch
    const int n0 = (blk & 255) * 16;
    const float* __restrict__ base = pts + (size_t)b * NPTS * 6;

    if (t < 96) qpt[t / 6][t % 6] = base[(size_t)(n0 + t / 6) * 6 + (t % 6)];
    __syncthreads();
    if (t < 256) {
        const int p = t >> 4;
        const int m = knn_idx[((size_t)b * NPTS + n0 + p) * KNBR + (t & 15)];
        const float cx = base[(size_t)m * 6 + 0];
        const float cy = base[(size_t)m * 6 + 1];
        const float cz = base[(size_t)m * 6 + 2];
        const float nx = base[(size_t)m * 6 + 3];
        const float ny = base[(size_t)m * 6 + 4];
        const float nz = base[(size_t)m * 6 + 5];
        rel[t][0] = cx - qpt[p][0];
        rel[t][1] = cy - qpt[p][1];
        rel[t][2] = cz - qpt[p][2];
        rel[t][3] = 0.0f;
        nin[t][0] = nx; nin[t][1] = ny; nin[t][2] = nz;
        nin[t][3] = 1.0f - (qpt[p][3] * nx + qpt[p][4] * ny + qpt[p][5] * nz);
    }
    __syncthreads();

    branch_compute<3>(rel, Wc1, bc1, bc2, wbuf + WC_HI, wbuf + WC_LO,
                      catH, catL, 0, w, l);
    branch_compute<4>(nin, Wn1, bn1, bn2, wbuf + WN_HI, wbuf + WN_LO,
                      catH, catL, 128, w, l);
    __syncthreads();

    // ---- output MLP layer 1: M=16 (points), N=128 (wave w -> cols 16w..16w+15), K=256
    {
        f32x4 a1 = (f32x4){0.f, 0.f, 0.f, 0.f};
        const int col = lr + 16 * w;
#pragma unroll
        for (int ks = 0; ks < 8; ++ks) {
            const int c0 = ks * 32 + kb;
            const bf16x8 ah = *(const bf16x8*)&catH[lr][c0];
            const bf16x8 al = *(const bf16x8*)&catL[lr][c0];
            const unsigned short* wp = wbuf + WO1_HI + ((size_t)col << 8) + c0;
            const bf16x8 bh = *(const bf16x8*)wp;
            const bf16x8 bl = *(const bf16x8*)(wp + (WO1_LO - WO1_HI));
            a1 = __builtin_amdgcn_mfma_f32_16x16x32_bf16(ah, bh, a1, 0, 0, 0);
            a1 = __builtin_amdgcn_mfma_f32_16x16x32_bf16(ah, bl, a1, 0, 0, 0);
            a1 = __builtin_amdgcn_mfma_f32_16x16x32_bf16(al, bh, a1, 0, 0, 0);
        }
        const float bo = bo1[col];
#pragma unroll
        for (int r = 0; r < 4; ++r) {
            const int prow = lq * 4 + r;
            const float x = gelu_f(a1[r] + bo);
            short hi, lo;
            bsplit(x, hi, lo);
            o1H[prow][col] = (unsigned short)hi;
            o1L[prow][col] = (unsigned short)lo;
        }
    }
    __syncthreads();
    // ---- output MLP layer 2: M=16, K=128
    {
        f32x4 a2 = (f32x4){0.f, 0.f, 0.f, 0.f};
        const int col = lr + 16 * w;
#pragma unroll
        for (int ks = 0; ks < 4; ++ks) {
            const int c0 = ks * 32 + kb;
            const bf16x8 ah = *(const bf16x8*)&o1H[lr][c0];
            const bf16x8 al = *(const bf16x8*)&o1L[lr][c0];
            const unsigned short* wp = wbuf + WO2_HI + ((size_t)col << 7) + c0;
            const bf16x8 bh = *(const bf16x8*)wp;
            const bf16x8 bl = *(const bf16x8*)(wp + (WO2_LO - WO2_HI));
            a2 = __builtin_amdgcn_mfma_f32_16x16x32_bf16(ah, bh, a2, 0, 0, 0);
            a2 = __builtin_amdgcn_mfma_f32_16x16x32_bf16(ah, bl, a2, 0, 0, 0);
            a2 = __builtin_amdgcn_mfma_f32_16x16x32_bf16(al, bh, a2, 0, 0, 0);
        }
        const float bo = bo2[col];
#pragma unroll
        for (int r = 0; r < 4; ++r) {
            const int prow = lq * 4 + r;
            outp[((size_t)b * NPTS + n0 + prow) * HDIM + col] = a2[r] + bo;
        }
    }
}

extern "C" void kernel_launch(void* const* d_in, const int* in_sizes, int n_in,
                              void* d_out, int out_size, void* d_ws, size_t ws_size,
                              hipStream_t stream) {
    const float* pts = (const float*)d_in[0];
    const float* Wc1 = (const float*)d_in[1];
    const float* bc1 = (const float*)d_in[2];
    const float* Wc2 = (const float*)d_in[3];
    const float* bc2 = (const float*)d_in[4];
    const float* Wn1 = (const float*)d_in[5];
    const float* bn1 = (const float*)d_in[6];
    const float* Wn2 = (const float*)d_in[7];
    const float* bn2 = (const float*)d_in[8];
    const float* Wo1 = (const float*)d_in[9];
    const float* bo1 = (const float*)d_in[10];
    const float* Wo2 = (const float*)d_in[11];
    const float* bo2 = (const float*)d_in[12];
    float* outp = (float*)d_out;
    int* idx = (int*)d_ws;
    unsigned short* wbuf = (unsigned short*)((char*)d_ws + WSOFF_W);

    prep_weights<<<dim3(320), dim3(256), 0, stream>>>(Wc2, Wn2, Wo1, Wo2, wbuf);
    knn_kernel<<<dim3(BATCH * NPTS), dim3(256), 0, stream>>>(pts, idx);
    mlp_mfma<<<dim3(BATCH * NPTS / 16), dim3(512), 0, stream>>>(
        pts, idx, Wc1, bc1, bc2, Wn1, bn1, bn2, bo1, bo2, wbuf, outp);
}

// Round 3
// 371.545 us; speedup vs baseline: 2.4481x; 1.0535x over previous
//
#include <hip/hip_runtime.h>
#include <math.h>

#define BATCH 4
#define NPTS 4096
#define KNBR 16
#define HDIM 128

typedef __attribute__((ext_vector_type(8))) short bf16x8;
typedef __attribute__((ext_vector_type(4))) float f32x4;

// ws layout: [0, 1MB): knn idx (int). [1MB, +320KB): split weights (ushort)
#define WSOFF_W (1u << 20)
#define WC_HI 0
#define WC_LO 16384
#define WN_HI 32768
#define WN_LO 49152
#define WO1_HI 65536
#define WO1_LO 98304
#define WO2_HI 131072
#define WO2_LO 147456

// branchless gelu: 0.5x(1+erf(x/sqrt2)), erf via A&S 7.1.26 (|err|<=1.5e-7)
__device__ __forceinline__ float gelu_f(float x) {
    const float z = x * 0.7071067811865476f;
    const float u = fabsf(z);
    const float z2 = z * z;
    const float t = __builtin_amdgcn_rcpf(fmaf(0.3275911f, u, 1.0f));
    const float E = __expf(-z2);
    float p = fmaf(t, 1.061405429f, -1.453152027f);
    p = fmaf(t, p, 1.421413741f);
    p = fmaf(t, p, -0.284496736f);
    p = fmaf(t, p, 0.254829592f);
    p = p * t;
    const float e = fmaf(-p, E, 1.0f);      // erf(|z|)
    const float hx = 0.5f * x;
    return fmaf(fabsf(hx), e, hx);
}

__device__ __forceinline__ unsigned long long umin64(unsigned long long a, unsigned long long b) {
    return a < b ? a : b;
}
__device__ __forceinline__ unsigned long long umax64(unsigned long long a, unsigned long long b) {
    return a > b ? a : b;
}

__device__ __forceinline__ void bsplit(float x, short& hi, short& lo) {
    const unsigned u = __float_as_uint(x);
    hi = (short)(u >> 16);
    const float r = x - __uint_as_float(u & 0xffff0000u);
    lo = (short)(__float_as_uint(r) >> 16);
}

// ---------------- weight transpose + hi/lo split ----------------
__global__ __launch_bounds__(256) void prep_weights(
    const float* __restrict__ Wc2, const float* __restrict__ Wn2,
    const float* __restrict__ Wo1, const float* __restrict__ Wo2,
    unsigned short* __restrict__ wbuf)
{
    const int e = blockIdx.x * 256 + threadIdx.x;   // 0..81919
    const float* src;
    unsigned short *dh, *dl;
    int klog, idx;
    if (e < 16384)      { src = Wc2; dh = wbuf + WC_HI;  dl = wbuf + WC_LO;  klog = 7; idx = e; }
    else if (e < 32768) { src = Wn2; dh = wbuf + WN_HI;  dl = wbuf + WN_LO;  klog = 7; idx = e - 16384; }
    else if (e < 65536) { src = Wo1; dh = wbuf + WO1_HI; dl = wbuf + WO1_LO; klog = 8; idx = e - 32768; }
    else                { src = Wo2; dh = wbuf + WO2_HI; dl = wbuf + WO2_LO; klog = 7; idx = e - 65536; }
    const int n = idx >> klog;
    const int k = idx & ((1 << klog) - 1);
    const float x = src[(k << 7) + n];         // src is [K][128] row-major
    short hi, lo;
    bsplit(x, hi, lo);
    dh[idx] = (unsigned short)hi;
    dl[idx] = (unsigned short)lo;
}

// ---------------- KNN v2: block=256thr per query; wave-local select + bitonic merge ----------------
__global__ __launch_bounds__(256) void knn_kernel(const float* __restrict__ pts,
                                                  int* __restrict__ idx_out) {
    const int bid = blockIdx.x;
    const int b = bid >> 12;
    const int n = bid & (NPTS - 1);
    const int t = threadIdx.x;
    const int lane = t & 63;
    const int w = t >> 6;
    const float* __restrict__ base = pts + (size_t)b * NPTS * 6;

    const float qx = base[(size_t)n * 6 + 0];
    const float qy = base[(size_t)n * 6 + 1];
    const float qz = base[(size_t)n * 6 + 2];
    const float sqn = qx * qx + qy * qy + qz * qz;

    unsigned long long keys[16];
#pragma unroll
    for (int j = 0; j < 16; ++j) {
        const int m = t + 256 * j;
        const float cx = base[(size_t)m * 6 + 0];
        const float cy = base[(size_t)m * 6 + 1];
        const float cz = base[(size_t)m * 6 + 2];
        const float sqm = cx * cx + cy * cy + cz * cz;
        const float dot = qx * cx + qy * cy + qz * cz;
        float d2 = (sqn + sqm) - 2.0f * dot;   // bit-identical to passing version
        d2 = fmaxf(d2, 0.0f);
        unsigned long long key =
            ((unsigned long long)__float_as_uint(d2) << 32) | (unsigned int)m;
        if (m == n) key = ~0ull;               // exclude self
        keys[j] = key;
    }

    // per-thread bitonic sort of 16 keys, ascending (all indices compile-time)
#pragma unroll
    for (int k = 2; k <= 16; k <<= 1) {
#pragma unroll
        for (int j = k >> 1; j > 0; j >>= 1) {
#pragma unroll
            for (int i = 0; i < 16; ++i) {
                const int p = i ^ j;
                if (p > i) {
                    const bool up = ((i & k) == 0);
                    const unsigned long long a = keys[i], bb = keys[p];
                    if ((a > bb) == up) { keys[i] = bb; keys[p] = a; }
                }
            }
        }
    }

    __shared__ unsigned long long top64[64];

    // wave-local selection: 16 rounds, no barriers
    unsigned long long head = keys[0];
    for (int r = 0; r < KNBR; ++r) {
        unsigned long long v = head;
#pragma unroll
        for (int s = 32; s >= 1; s >>= 1)
            v = umin64(v, __shfl_xor(v, s, 64));
        if (head == v) {   // unique winner pops (keys embed index -> distinct)
#pragma unroll
            for (int j = 0; j < 15; ++j) keys[j] = keys[j + 1];
            keys[15] = ~0ull;
        }
        head = keys[0];
        if (lane == 0) top64[w * 16 + r] = v;
    }
    __syncthreads();

    // wave 0: bitonic sort the 64 per-wave winners, emit global top-16
    if (t < 64) {
        unsigned long long v = top64[t];
#pragma unroll
        for (int k = 2; k <= 64; k <<= 1) {
#pragma unroll
            for (int j = k >> 1; j > 0; j >>= 1) {
                const unsigned long long p = __shfl_xor(v, j, 64);
                const bool keepmin = (((t & j) == 0) == ((t & k) == 0));
                v = keepmin ? umin64(v, p) : umax64(v, p);
            }
        }
        if (t < KNBR)
            idx_out[((size_t)b * NPTS + n) * KNBR + t] = (int)(v & 0xffffffffull);
    }
}

// ---------------- branch compute: layer1 (VALU) + layer2 (MFMA) + k-max ----------------
template<int NIN>
__device__ __forceinline__ void branch_compute(
    const float (* __restrict__ inp)[4],           // 128 rows x 4 (LDS)
    const float* __restrict__ W1,                  // [NIN][128] fp32 global
    const float* __restrict__ b1,
    const float* __restrict__ b2,
    const unsigned short* __restrict__ w2hi,       // [128][128] bf16 (N-major)
    const unsigned short* __restrict__ w2lo,
    unsigned short (* __restrict__ catH)[264],
    unsigned short (* __restrict__ catL)[264],
    int colbase, int w, int l)
{
    const int lr = l & 15;
    const int lq = l >> 4;
    const int kb = lq * 8;

    f32x4 acc[2][8];
#pragma unroll
    for (int rt = 0; rt < 2; ++rt)
#pragma unroll
        for (int ct = 0; ct < 8; ++ct)
            acc[rt][ct] = (f32x4){0.f, 0.f, 0.f, 0.f};

    for (int ks = 0; ks < 4; ++ks) {
        const int c0 = ks * 32 + kb;
        // layer-1 weights/bias for this lane's 8 columns
        float wr[NIN][8], bb[8];
#pragma unroll
        for (int d = 0; d < NIN; ++d) {
            *(float4*)&wr[d][0] = *(const float4*)(W1 + (d << 7) + c0);
            *(float4*)&wr[d][4] = *(const float4*)(W1 + (d << 7) + c0 + 4);
        }
        *(float4*)&bb[0] = *(const float4*)(b1 + c0);
        *(float4*)&bb[4] = *(const float4*)(b1 + c0 + 4);

        bf16x8 ah[2], al[2];
#pragma unroll
        for (int rt = 0; rt < 2; ++rt) {
            const int row = 32 * w + 16 * rt + lr;
            const float4 rv = *(const float4*)&inp[row][0];
#pragma unroll
            for (int jj = 0; jj < 8; ++jj) {
                float x = bb[jj] + rv.x * wr[0][jj] + rv.y * wr[1][jj] + rv.z * wr[2][jj];
                if (NIN == 4) x += rv.w * wr[3][jj];
                x = gelu_f(x);
                short hi, lo;
                bsplit(x, hi, lo);
                ah[rt][jj] = hi;
                al[rt][jj] = lo;
            }
        }
#pragma unroll
        for (int ct = 0; ct < 8; ++ct) {
            const unsigned short* wp = w2hi + (((lr + 16 * ct) << 7) + c0);
            const unsigned short* wq = w2lo + (((lr + 16 * ct) << 7) + c0);
            const bf16x8 bh = *(const bf16x8*)wp;
            const bf16x8 bl = *(const bf16x8*)wq;
#pragma unroll
            for (int rt = 0; rt < 2; ++rt) {
                acc[rt][ct] = __builtin_amdgcn_mfma_f32_16x16x32_bf16(ah[rt], bh, acc[rt][ct], 0, 0, 0);
                acc[rt][ct] = __builtin_amdgcn_mfma_f32_16x16x32_bf16(ah[rt], bl, acc[rt][ct], 0, 0, 0);
                acc[rt][ct] = __builtin_amdgcn_mfma_f32_16x16x32_bf16(al[rt], bh, acc[rt][ct], 0, 0, 0);
            }
        }
    }
    // k-max over 16 neighbors + bias + split to cat
#pragma unroll
    for (int rt = 0; rt < 2; ++rt) {
        const int p = 2 * w + rt;
#pragma unroll
        for (int ct = 0; ct < 8; ++ct) {
            const f32x4 a = acc[rt][ct];
            float m = fmaxf(fmaxf(a[0], a[1]), fmaxf(a[2], a[3]));
            m = fmaxf(m, __shfl_xor(m, 16));
            m = fmaxf(m, __shfl_xor(m, 32));
            const int col = lr + 16 * ct;
            const float v = m + b2[col];
            if (lq == 0) {
                short hi, lo;
                bsplit(v, hi, lo);
                catH[p][colbase + col] = (unsigned short)hi;
                catL[p][colbase + col] = (unsigned short)lo;
            }
        }
    }
}

// ---------------- fused MLP with MFMA: one block (256 thr) per 8 points ----------------
__global__ __launch_bounds__(256, 3) void mlp_mfma(
    const float* __restrict__ pts, const int* __restrict__ knn_idx,
    const float* __restrict__ Wc1, const float* __restrict__ bc1,
    const float* __restrict__ bc2,
    const float* __restrict__ Wn1, const float* __restrict__ bn1,
    const float* __restrict__ bn2,
    const float* __restrict__ bo1, const float* __restrict__ bo2,
    const unsigned short* __restrict__ wbuf,
    float* __restrict__ outp)
{
    __shared__ __align__(16) float rel[128][4];
    __shared__ __align__(16) float nin[128][4];
    __shared__ float qpt[8][6];
    __shared__ __align__(16) unsigned short catH[8][264];
    __shared__ __align__(16) unsigned short catL[8][264];
    __shared__ __align__(16) unsigned short o1H[8][136];
    __shared__ __align__(16) unsigned short o1L[8][136];

    const int t = threadIdx.x;
    const int w = t >> 6;
    const int l = t & 63;
    const int lr = l & 15;
    const int lq = l >> 4;
    const int kb = lq * 8;
    const int blk = blockIdx.x;
    const int b = blk >> 9;                 // 512 blocks per batch
    const int n0 = (blk & 511) * 8;
    const float* __restrict__ base = pts + (size_t)b * NPTS * 6;

    if (t < 48) qpt[t / 6][t % 6] = base[(size_t)(n0 + t / 6) * 6 + (t % 6)];
    __syncthreads();
    if (t < 128) {
        const int p = t >> 4;
        const int m = knn_idx[((size_t)b * NPTS + n0 + p) * KNBR + (t & 15)];
        const float cx = base[(size_t)m * 6 + 0];
        const float cy = base[(size_t)m * 6 + 1];
        const float cz = base[(size_t)m * 6 + 2];
        const float nx = base[(size_t)m * 6 + 3];
        const float ny = base[(size_t)m * 6 + 4];
        const float nz = base[(size_t)m * 6 + 5];
        rel[t][0] = cx - qpt[p][0];
        rel[t][1] = cy - qpt[p][1];
        rel[t][2] = cz - qpt[p][2];
        rel[t][3] = 0.0f;
        nin[t][0] = nx; nin[t][1] = ny; nin[t][2] = nz;
        nin[t][3] = 1.0f - (qpt[p][3] * nx + qpt[p][4] * ny + qpt[p][5] * nz);
    }
    __syncthreads();

    branch_compute<3>(rel, Wc1, bc1, bc2, wbuf + WC_HI, wbuf + WC_LO,
                      catH, catL, 0, w, l);
    branch_compute<4>(nin, Wn1, bn1, bn2, wbuf + WN_HI, wbuf + WN_LO,
                      catH, catL, 128, w, l);
    __syncthreads();

    // ---- output MLP layer 1: M=8 pts, wave w -> col tiles 2w, 2w+1; K=256
    {
        f32x4 a1[2];
        a1[0] = (f32x4){0.f, 0.f, 0.f, 0.f};
        a1[1] = (f32x4){0.f, 0.f, 0.f, 0.f};
#pragma unroll
        for (int ks = 0; ks < 8; ++ks) {
            const int c0 = ks * 32 + kb;
            const bf16x8 ah = *(const bf16x8*)&catH[lr & 7][c0];
            const bf16x8 al = *(const bf16x8*)&catL[lr & 7][c0];
#pragma unroll
            for (int c2 = 0; c2 < 2; ++c2) {
                const int col = lr + 16 * (2 * w + c2);
                const unsigned short* wp = wbuf + WO1_HI + ((size_t)col << 8) + c0;
                const bf16x8 bh = *(const bf16x8*)wp;
                const bf16x8 bl = *(const bf16x8*)(wp + (WO1_LO - WO1_HI));
                a1[c2] = __builtin_amdgcn_mfma_f32_16x16x32_bf16(ah, bh, a1[c2], 0, 0, 0);
                a1[c2] = __builtin_amdgcn_mfma_f32_16x16x32_bf16(ah, bl, a1[c2], 0, 0, 0);
                a1[c2] = __builtin_amdgcn_mfma_f32_16x16x32_bf16(al, bh, a1[c2], 0, 0, 0);
            }
        }
#pragma unroll
        for (int c2 = 0; c2 < 2; ++c2) {
            const int col = lr + 16 * (2 * w + c2);
            const float bo = bo1[col];
#pragma unroll
            for (int r = 0; r < 4; ++r) {
                const int prow = lq * 4 + r;
                if (prow < 8) {
                    const float x = gelu_f(a1[c2][r] + bo);
                    short hi, lo;
                    bsplit(x, hi, lo);
                    o1H[prow][col] = (unsigned short)hi;
                    o1L[prow][col] = (unsigned short)lo;
                }
            }
        }
    }
    __syncthreads();
    // ---- output MLP layer 2: M=8, K=128
    {
        f32x4 a2[2];
        a2[0] = (f32x4){0.f, 0.f, 0.f, 0.f};
        a2[1] = (f32x4){0.f, 0.f, 0.f, 0.f};
#pragma unroll
        for (int ks = 0; ks < 4; ++ks) {
            const int c0 = ks * 32 + kb;
            const bf16x8 ah = *(const bf16x8*)&o1H[lr & 7][c0];
            const bf16x8 al = *(const bf16x8*)&o1L[lr & 7][c0];
#pragma unroll
            for (int c2 = 0; c2 < 2; ++c2) {
                const int col = lr + 16 * (2 * w + c2);
                const unsigned short* wp = wbuf + WO2_HI + ((size_t)col << 7) + c0;
                const bf16x8 bh = *(const bf16x8*)wp;
                const bf16x8 bl = *(const bf16x8*)(wp + (WO2_LO - WO2_HI));
                a2[c2] = __builtin_amdgcn_mfma_f32_16x16x32_bf16(ah, bh, a2[c2], 0, 0, 0);
                a2[c2] = __builtin_amdgcn_mfma_f32_16x16x32_bf16(ah, bl, a2[c2], 0, 0, 0);
                a2[c2] = __builtin_amdgcn_mfma_f32_16x16x32_bf16(al, bh, a2[c2], 0, 0, 0);
            }
        }
#pragma unroll
        for (int c2 = 0; c2 < 2; ++c2) {
            const int col = lr + 16 * (2 * w + c2);
            const float bo = bo2[col];
#pragma unroll
            for (int r = 0; r < 4; ++r) {
                const int prow = lq * 4 + r;
                if (prow < 8)
                    outp[((size_t)b * NPTS + n0 + prow) * HDIM + col] = a2[c2][r] + bo;
            }
        }
    }
}

extern "C" void kernel_launch(void* const* d_in, const int* in_sizes, int n_in,
                              void* d_out, int out_size, void* d_ws, size_t ws_size,
                              hipStream_t stream) {
    const float* pts = (const float*)d_in[0];
    const float* Wc1 = (const float*)d_in[1];
    const float* bc1 = (const float*)d_in[2];
    const float* Wc2 = (const float*)d_in[3];
    const float* bc2 = (const float*)d_in[4];
    const float* Wn1 = (const float*)d_in[5];
    const float* bn1 = (const float*)d_in[6];
    const float* Wn2 = (const float*)d_in[7];
    const float* bn2 = (const float*)d_in[8];
    const float* Wo1 = (const float*)d_in[9];
    const float* bo1 = (const float*)d_in[10];
    const float* Wo2 = (const float*)d_in[11];
    const float* bo2 = (const float*)d_in[12];
    float* outp = (float*)d_out;
    int* idx = (int*)d_ws;
    unsigned short* wbuf = (unsigned short*)((char*)d_ws + WSOFF_W);

    prep_weights<<<dim3(320), dim3(256), 0, stream>>>(Wc2, Wn2, Wo1, Wo2, wbuf);
    knn_kernel<<<dim3(BATCH * NPTS), dim3(256), 0, stream>>>(pts, idx);
    mlp_mfma<<<dim3(BATCH * NPTS / 8), dim3(256), 0, stream>>>(
        pts, idx, Wc1, bc1, bc2, Wn1, bn1, bn2, bo1, bo2, wbuf, outp);
}

// Round 4
// 267.731 us; speedup vs baseline: 3.3973x; 1.3878x over previous
//
#include <hip/hip_runtime.h>
#include <math.h>

#define BATCH 4
#define NPTS 4096
#define KNBR 16
#define HDIM 128

typedef __attribute__((ext_vector_type(8))) short bf16x8;
typedef __attribute__((ext_vector_type(4))) float f32x4;

// ws layout: [0,1MB): knn idx (int).
// [1MB, +320KB): phase A = ctab (float4, 256KB, used by knn);
//                phase B = frag-packed split weights (ushort, 320KB, used by mlp).
// Safe because stream order is: prep_points -> knn -> prep_weights -> mlp.
#define WSOFF_W (1u << 20)
#define WC_HI 0
#define WC_LO 16384
#define WN_HI 32768
#define WN_LO 49152
#define WO1_HI 65536
#define WO1_LO 98304
#define WO2_HI 131072
#define WO2_LO 147456

// branchless gelu: 0.5x(1+erf(x/sqrt2)), erf via A&S 7.1.26 (|err|<=1.5e-7)
__device__ __forceinline__ float gelu_f(float x) {
    const float z = x * 0.7071067811865476f;
    const float u = fabsf(z);
    const float z2 = z * z;
    const float t = __builtin_amdgcn_rcpf(fmaf(0.3275911f, u, 1.0f));
    const float E = __expf(-z2);
    float p = fmaf(t, 1.061405429f, -1.453152027f);
    p = fmaf(t, p, 1.421413741f);
    p = fmaf(t, p, -0.284496736f);
    p = fmaf(t, p, 0.254829592f);
    p = p * t;
    const float e = fmaf(-p, E, 1.0f);      // erf(|z|)
    const float hx = 0.5f * x;
    return fmaf(fabsf(hx), e, hx);
}

__device__ __forceinline__ unsigned long long umin64(unsigned long long a, unsigned long long b) {
    return a < b ? a : b;
}
__device__ __forceinline__ unsigned long long umax64(unsigned long long a, unsigned long long b) {
    return a > b ? a : b;
}

__device__ __forceinline__ void bsplit(float x, short& hi, short& lo) {
    const unsigned u = __float_as_uint(x);
    hi = (short)(u >> 16);
    const float r = x - __uint_as_float(u & 0xffff0000u);
    lo = (short)(__float_as_uint(r) >> 16);
}

// one DPP min step on a u64 key (invalid source lanes read ~0 = identity)
template<int CTRL>
__device__ __forceinline__ unsigned long long dpp_min_step(unsigned long long v) {
    const unsigned lo = (unsigned)v;
    const unsigned hi = (unsigned)(v >> 32);
    const unsigned plo = (unsigned)__builtin_amdgcn_update_dpp(
        (int)0xFFFFFFFF, (int)lo, CTRL, 0xF, 0xF, false);
    const unsigned phi = (unsigned)__builtin_amdgcn_update_dpp(
        (int)0xFFFFFFFF, (int)hi, CTRL, 0xF, 0xF, false);
    const unsigned long long p = ((unsigned long long)phi << 32) | plo;
    return v < p ? v : p;
}

// ---------------- candidate table: (x,y,z,|p|^2) ----------------
__global__ __launch_bounds__(256) void prep_points(const float* __restrict__ pts,
                                                   float4* __restrict__ ctab) {
    const int e = blockIdx.x * 256 + threadIdx.x;     // 0..16383
    const float* __restrict__ p = pts + (size_t)e * 6;
    const float x = p[0], y = p[1], z = p[2];
    const float sq = x * x + y * y + z * z;
    ctab[e] = make_float4(x, y, z, sq);
}

// ---------------- weight transpose + hi/lo split, MFMA-fragment-packed ----------------
// layout per table: frag[(ks*8 + ct)*64 + lane][8]; lane holds B[k][col] with
// col=(lane&15)+16*ct, k=ks*32+(lane>>4)*8+j  -> wave loads are 1KB contiguous.
__global__ __launch_bounds__(256) void prep_weights(
    const float* __restrict__ Wc2, const float* __restrict__ Wn2,
    const float* __restrict__ Wo1, const float* __restrict__ Wo2,
    unsigned short* __restrict__ wbuf)
{
    const int e = blockIdx.x * 256 + threadIdx.x;   // 0..81919
    const float* src;
    unsigned short *dh, *dl;
    int idx;
    if (e < 16384)      { src = Wc2; dh = wbuf + WC_HI;  dl = wbuf + WC_LO;  idx = e; }
    else if (e < 32768) { src = Wn2; dh = wbuf + WN_HI;  dl = wbuf + WN_LO;  idx = e - 16384; }
    else if (e < 65536) { src = Wo1; dh = wbuf + WO1_HI; dl = wbuf + WO1_LO; idx = e - 32768; }
    else                { src = Wo2; dh = wbuf + WO2_HI; dl = wbuf + WO2_LO; idx = e - 65536; }
    const int j = idx & 7;
    const int l = (idx >> 3) & 63;
    const int tile = idx >> 9;
    const int ct = tile & 7;
    const int ks = tile >> 3;
    const int n = (l & 15) + 16 * ct;
    const int k = ks * 32 + ((l >> 4) << 3) + j;
    const float x = src[k * 128 + n];          // src is [K][128] row-major
    short hi, lo;
    bsplit(x, hi, lo);
    dh[idx] = (unsigned short)hi;
    dl[idx] = (unsigned short)lo;
}

// ---------------- KNN v3: per-thread sort + DPP-reduce rounds + bitonic merge ----------------
__global__ __launch_bounds__(256) void knn_kernel(const float4* __restrict__ ctab,
                                                  int* __restrict__ idx_out) {
    const int bid = blockIdx.x;
    const int b = bid >> 12;
    const int n = bid & (NPTS - 1);
    const int t = threadIdx.x;
    const int lane = t & 63;
    const int w = t >> 6;
    const float4* __restrict__ cb = ctab + (size_t)b * NPTS;

    const float4 q = cb[n];                    // qx,qy,qz,sqn
    unsigned long long keys[16];
#pragma unroll
    for (int j = 0; j < 16; ++j) {
        const int m = t + 256 * j;
        const float4 c = cb[m];
        const float dot = q.x * c.x + q.y * c.y + q.z * c.z;
        float d2 = (q.w + c.w) - 2.0f * dot;
        d2 = fmaxf(d2, 0.0f);
        unsigned long long key =
            ((unsigned long long)__float_as_uint(d2) << 32) | (unsigned int)m;
        if (m == n) key = ~0ull;               // exclude self
        keys[j] = key;
    }

    // per-thread bitonic sort of 16 keys, ascending
#pragma unroll
    for (int k = 2; k <= 16; k <<= 1) {
#pragma unroll
        for (int j = k >> 1; j > 0; j >>= 1) {
#pragma unroll
            for (int i = 0; i < 16; ++i) {
                const int p = i ^ j;
                if (p > i) {
                    const bool up = ((i & k) == 0);
                    const unsigned long long a = keys[i], bb = keys[p];
                    if ((a > bb) == up) { keys[i] = bb; keys[p] = a; }
                }
            }
        }
    }

    __shared__ unsigned long long top64[64];

    // wave-local selection: 16 rounds, DPP min-reduce (result lands in lane 63)
    unsigned long long head = keys[0];
    for (int r = 0; r < KNBR; ++r) {
        unsigned long long v = head;
        v = dpp_min_step<0x111>(v);   // row_shr:1
        v = dpp_min_step<0x112>(v);   // row_shr:2
        v = dpp_min_step<0x114>(v);   // row_shr:4
        v = dpp_min_step<0x118>(v);   // row_shr:8
        v = dpp_min_step<0x142>(v);   // row_bcast:15
        v = dpp_min_step<0x143>(v);   // row_bcast:31
        const unsigned glo = (unsigned)__builtin_amdgcn_readlane((int)(unsigned)v, 63);
        const unsigned ghi = (unsigned)__builtin_amdgcn_readlane((int)(v >> 32), 63);
        const unsigned long long g = ((unsigned long long)ghi << 32) | glo;
        if (lane == 0) top64[w * 16 + r] = g;
        if (head == g) {   // unique owner pops its sorted head
#pragma unroll
            for (int j = 0; j < 15; ++j) keys[j] = keys[j + 1];
            keys[15] = ~0ull;
        }
        head = keys[0];
    }
    __syncthreads();

    // wave 0: bitonic sort the 64 per-wave winners, emit global top-16
    if (t < 64) {
        unsigned long long v = top64[t];
#pragma unroll
        for (int k = 2; k <= 64; k <<= 1) {
#pragma unroll
            for (int j = k >> 1; j > 0; j >>= 1) {
                const unsigned long long p = __shfl_xor(v, j, 64);
                const bool keepmin = (((t & j) == 0) == ((t & k) == 0));
                v = keepmin ? umin64(v, p) : umax64(v, p);
            }
        }
        if (t < KNBR)
            idx_out[((size_t)b * NPTS + n) * KNBR + t] = (int)(v & 0xffffffffull);
    }
}

// ---------------- branch compute: layer1 (VALU) + layer2 (MFMA) + k-max ----------------
template<int NIN>
__device__ __forceinline__ void branch_compute(
    const float (* __restrict__ inp)[4],           // 128 rows x 4 (LDS)
    const float* __restrict__ W1,                  // [NIN][128] fp32 global
    const float* __restrict__ b1,
    const float* __restrict__ b2,
    const unsigned short* __restrict__ w2hi,       // frag-packed [32 tiles][64][8]
    const unsigned short* __restrict__ w2lo,
    unsigned short (* __restrict__ catH)[264],
    unsigned short (* __restrict__ catL)[264],
    int colbase, int w, int l)
{
    const int lr = l & 15;
    const int lq = l >> 4;
    const int kb = lq * 8;

    f32x4 acc[2][8];
#pragma unroll
    for (int rt = 0; rt < 2; ++rt)
#pragma unroll
        for (int ct = 0; ct < 8; ++ct)
            acc[rt][ct] = (f32x4){0.f, 0.f, 0.f, 0.f};

    for (int ks = 0; ks < 4; ++ks) {
        const int c0 = ks * 32 + kb;
        // 1) issue ALL B-fragment loads (coalesced 1KB per wave-load)
        bf16x8 bh[8], bl[8];
        const unsigned short* fb = w2hi + ((size_t)(ks * 8) * 64 + l) * 8;
        const unsigned short* fq = w2lo + ((size_t)(ks * 8) * 64 + l) * 8;
#pragma unroll
        for (int ct = 0; ct < 8; ++ct) {
            bh[ct] = *(const bf16x8*)(fb + ct * 512);
            bl[ct] = *(const bf16x8*)(fq + ct * 512);
        }
        // 2) layer-1 + gelu + split (long VALU stretch hides the loads)
        float wr[NIN][8], bb[8];
#pragma unroll
        for (int d = 0; d < NIN; ++d) {
            *(float4*)&wr[d][0] = *(const float4*)(W1 + (d << 7) + c0);
            *(float4*)&wr[d][4] = *(const float4*)(W1 + (d << 7) + c0 + 4);
        }
        *(float4*)&bb[0] = *(const float4*)(b1 + c0);
        *(float4*)&bb[4] = *(const float4*)(b1 + c0 + 4);

        bf16x8 ah[2], al[2];
#pragma unroll
        for (int rt = 0; rt < 2; ++rt) {
            const int row = 32 * w + 16 * rt + lr;
            const float4 rv = *(const float4*)&inp[row][0];
#pragma unroll
            for (int jj = 0; jj < 8; ++jj) {
                float x = bb[jj] + rv.x * wr[0][jj] + rv.y * wr[1][jj] + rv.z * wr[2][jj];
                if (NIN == 4) x += rv.w * wr[3][jj];
                x = gelu_f(x);
                short hi, lo;
                bsplit(x, hi, lo);
                ah[rt][jj] = hi;
                al[rt][jj] = lo;
            }
        }
        // 3) MFMA cluster
#pragma unroll
        for (int ct = 0; ct < 8; ++ct) {
#pragma unroll
            for (int rt = 0; rt < 2; ++rt) {
                acc[rt][ct] = __builtin_amdgcn_mfma_f32_16x16x32_bf16(ah[rt], bh[ct], acc[rt][ct], 0, 0, 0);
                acc[rt][ct] = __builtin_amdgcn_mfma_f32_16x16x32_bf16(ah[rt], bl[ct], acc[rt][ct], 0, 0, 0);
                acc[rt][ct] = __builtin_amdgcn_mfma_f32_16x16x32_bf16(al[rt], bh[ct], acc[rt][ct], 0, 0, 0);
            }
        }
    }
    // k-max over 16 neighbors + bias + split to cat
#pragma unroll
    for (int rt = 0; rt < 2; ++rt) {
        const int p = 2 * w + rt;
#pragma unroll
        for (int ct = 0; ct < 8; ++ct) {
            const f32x4 a = acc[rt][ct];
            float m = fmaxf(fmaxf(a[0], a[1]), fmaxf(a[2], a[3]));
            m = fmaxf(m, __shfl_xor(m, 16));
            m = fmaxf(m, __shfl_xor(m, 32));
            const int col = lr + 16 * ct;
            const float v = m + b2[col];
            if (lq == 0) {
                short hi, lo;
                bsplit(v, hi, lo);
                catH[p][colbase + col] = (unsigned short)hi;
                catL[p][colbase + col] = (unsigned short)lo;
            }
        }
    }
}

// ---------------- fused MLP with MFMA: one block (256 thr) per 8 points ----------------
__global__ __launch_bounds__(256, 3) void mlp_mfma(
    const float* __restrict__ pts, const int* __restrict__ knn_idx,
    const float* __restrict__ Wc1, const float* __restrict__ bc1,
    const float* __restrict__ bc2,
    const float* __restrict__ Wn1, const float* __restrict__ bn1,
    const float* __restrict__ bn2,
    const float* __restrict__ bo1, const float* __restrict__ bo2,
    const unsigned short* __restrict__ wbuf,
    float* __restrict__ outp)
{
    __shared__ __align__(16) float rel[128][4];
    __shared__ __align__(16) float nin[128][4];
    __shared__ float qpt[8][6];
    __shared__ __align__(16) unsigned short catH[8][264];
    __shared__ __align__(16) unsigned short catL[8][264];
    __shared__ __align__(16) unsigned short o1H[8][136];
    __shared__ __align__(16) unsigned short o1L[8][136];

    const int t = threadIdx.x;
    const int w = t >> 6;
    const int l = t & 63;
    const int lr = l & 15;
    const int lq = l >> 4;
    const int kb = lq * 8;
    const int blk = blockIdx.x;
    const int b = blk >> 9;                 // 512 blocks per batch
    const int n0 = (blk & 511) * 8;
    const float* __restrict__ base = pts + (size_t)b * NPTS * 6;

    if (t < 48) qpt[t / 6][t % 6] = base[(size_t)(n0 + t / 6) * 6 + (t % 6)];
    __syncthreads();
    if (t < 128) {
        const int p = t >> 4;
        const int m = knn_idx[((size_t)b * NPTS + n0 + p) * KNBR + (t & 15)];
        const float cx = base[(size_t)m * 6 + 0];
        const float cy = base[(size_t)m * 6 + 1];
        const float cz = base[(size_t)m * 6 + 2];
        const float nx = base[(size_t)m * 6 + 3];
        const float ny = base[(size_t)m * 6 + 4];
        const float nz = base[(size_t)m * 6 + 5];
        rel[t][0] = cx - qpt[p][0];
        rel[t][1] = cy - qpt[p][1];
        rel[t][2] = cz - qpt[p][2];
        rel[t][3] = 0.0f;
        nin[t][0] = nx; nin[t][1] = ny; nin[t][2] = nz;
        nin[t][3] = 1.0f - (qpt[p][3] * nx + qpt[p][4] * ny + qpt[p][5] * nz);
    }
    __syncthreads();

    branch_compute<3>(rel, Wc1, bc1, bc2, wbuf + WC_HI, wbuf + WC_LO,
                      catH, catL, 0, w, l);
    branch_compute<4>(nin, Wn1, bn1, bn2, wbuf + WN_HI, wbuf + WN_LO,
                      catH, catL, 128, w, l);
    __syncthreads();

    // ---- output MLP layer 1: M=8 pts, wave w -> col tiles 2w, 2w+1; K=256 (8 ks)
    {
        f32x4 a1[2];
        a1[0] = (f32x4){0.f, 0.f, 0.f, 0.f};
        a1[1] = (f32x4){0.f, 0.f, 0.f, 0.f};
#pragma unroll
        for (int ks = 0; ks < 8; ++ks) {
            const int c0 = ks * 32 + kb;
            const bf16x8 ah = *(const bf16x8*)&catH[lr & 7][c0];
            const bf16x8 al = *(const bf16x8*)&catL[lr & 7][c0];
#pragma unroll
            for (int c2 = 0; c2 < 2; ++c2) {
                const int ct = 2 * w + c2;
                const unsigned short* wp = wbuf + WO1_HI + ((size_t)((ks * 8 + ct) * 64 + l)) * 8;
                const bf16x8 bh = *(const bf16x8*)wp;
                const bf16x8 bl = *(const bf16x8*)(wp + (WO1_LO - WO1_HI));
                a1[c2] = __builtin_amdgcn_mfma_f32_16x16x32_bf16(ah, bh, a1[c2], 0, 0, 0);
                a1[c2] = __builtin_amdgcn_mfma_f32_16x16x32_bf16(ah, bl, a1[c2], 0, 0, 0);
                a1[c2] = __builtin_amdgcn_mfma_f32_16x16x32_bf16(al, bh, a1[c2], 0, 0, 0);
            }
        }
#pragma unroll
        for (int c2 = 0; c2 < 2; ++c2) {
            const int col = lr + 16 * (2 * w + c2);
            const float bo = bo1[col];
#pragma unroll
            for (int r = 0; r < 4; ++r) {
                const int prow = lq * 4 + r;
                if (prow < 8) {
                    const float x = gelu_f(a1[c2][r] + bo);
                    short hi, lo;
                    bsplit(x, hi, lo);
                    o1H[prow][col] = (unsigned short)hi;
                    o1L[prow][col] = (unsigned short)lo;
                }
            }
        }
    }
    __syncthreads();
    // ---- output MLP layer 2: M=8, K=128 (4 ks)
    {
        f32x4 a2[2];
        a2[0] = (f32x4){0.f, 0.f, 0.f, 0.f};
        a2[1] = (f32x4){0.f, 0.f, 0.f, 0.f};
#pragma unroll
        for (int ks = 0; ks < 4; ++ks) {
            const int c0 = ks * 32 + kb;
            const bf16x8 ah = *(const bf16x8*)&o1H[lr & 7][c0];
            const bf16x8 al = *(const bf16x8*)&o1L[lr & 7][c0];
#pragma unroll
            for (int c2 = 0; c2 < 2; ++c2) {
                const int ct = 2 * w + c2;
                const unsigned short* wp = wbuf + WO2_HI + ((size_t)((ks * 8 + ct) * 64 + l)) * 8;
                const bf16x8 bh = *(const bf16x8*)wp;
                const bf16x8 bl = *(const bf16x8*)(wp + (WO2_LO - WO2_HI));
                a2[c2] = __builtin_amdgcn_mfma_f32_16x16x32_bf16(ah, bh, a2[c2], 0, 0, 0);
                a2[c2] = __builtin_amdgcn_mfma_f32_16x16x32_bf16(ah, bl, a2[c2], 0, 0, 0);
                a2[c2] = __builtin_amdgcn_mfma_f32_16x16x32_bf16(al, bh, a2[c2], 0, 0, 0);
            }
        }
#pragma unroll
        for (int c2 = 0; c2 < 2; ++c2) {
            const int col = lr + 16 * (2 * w + c2);
            const float bo = bo2[col];
#pragma unroll
            for (int r = 0; r < 4; ++r) {
                const int prow = lq * 4 + r;
                if (prow < 8)
                    outp[((size_t)b * NPTS + n0 + prow) * HDIM + col] = a2[c2][r] + bo;
            }
        }
    }
}

extern "C" void kernel_launch(void* const* d_in, const int* in_sizes, int n_in,
                              void* d_out, int out_size, void* d_ws, size_t ws_size,
                              hipStream_t stream) {
    const float* pts = (const float*)d_in[0];
    const float* Wc1 = (const float*)d_in[1];
    const float* bc1 = (const float*)d_in[2];
    const float* Wc2 = (const float*)d_in[3];
    const float* bc2 = (const float*)d_in[4];
    const float* Wn1 = (const float*)d_in[5];
    const float* bn1 = (const float*)d_in[6];
    const float* Wn2 = (const float*)d_in[7];
    const float* bn2 = (const float*)d_in[8];
    const float* Wo1 = (const float*)d_in[9];
    const float* bo1 = (const float*)d_in[10];
    const float* Wo2 = (const float*)d_in[11];
    const float* bo2 = (const float*)d_in[12];
    float* outp = (float*)d_out;
    int* idx = (int*)d_ws;
    float4* ctab = (float4*)((char*)d_ws + WSOFF_W);            // phase A
    unsigned short* wbuf = (unsigned short*)((char*)d_ws + WSOFF_W);  // phase B (after knn)

    prep_points<<<dim3(BATCH * NPTS / 256), dim3(256), 0, stream>>>(pts, ctab);
    knn_kernel<<<dim3(BATCH * NPTS), dim3(256), 0, stream>>>(ctab, idx);
    prep_weights<<<dim3(320), dim3(256), 0, stream>>>(Wc2, Wn2, Wo1, Wo2, wbuf);
    mlp_mfma<<<dim3(BATCH * NPTS / 8), dim3(256), 0, stream>>>(
        pts, idx, Wc1, bc1, bc2, Wn1, bn1, bn2, bo1, bo2, wbuf, outp);
}

// Round 5
// 190.168 us; speedup vs baseline: 4.7830x; 1.4079x over previous
//
#include <hip/hip_runtime.h>
#include <math.h>

#define BATCH 4
#define NPTS 4096
#define KNBR 16
#define HDIM 128

typedef __attribute__((ext_vector_type(8))) short bf16x8;
typedef __attribute__((ext_vector_type(4))) float f32x4;
typedef unsigned long long u64;

// ws layout: [0,1MB): knn idx (int).
// [1MB, +320KB): phase A = ctab (float4, 256KB, used by knn);
//                phase B = frag-packed split weights (ushort, 320KB, used by mlp).
// Safe because stream order is: prep_points -> knn -> prep_weights -> mlp.
#define WSOFF_W (1u << 20)
#define WC_HI 0
#define WC_LO 16384
#define WN_HI 32768
#define WN_LO 49152
#define WO1_HI 65536
#define WO1_LO 98304
#define WO2_HI 131072
#define WO2_LO 147456

// branchless gelu: 0.5x(1+erf(x/sqrt2)), erf via A&S 7.1.26 (|err|<=1.5e-7)
__device__ __forceinline__ float gelu_f(float x) {
    const float z = x * 0.7071067811865476f;
    const float u = fabsf(z);
    const float z2 = z * z;
    const float t = __builtin_amdgcn_rcpf(fmaf(0.3275911f, u, 1.0f));
    const float E = __expf(-z2);
    float p = fmaf(t, 1.061405429f, -1.453152027f);
    p = fmaf(t, p, 1.421413741f);
    p = fmaf(t, p, -0.284496736f);
    p = fmaf(t, p, 0.254829592f);
    p = p * t;
    const float e = fmaf(-p, E, 1.0f);      // erf(|z|)
    const float hx = 0.5f * x;
    return fmaf(fabsf(hx), e, hx);
}

__device__ __forceinline__ void bsplit(float x, short& hi, short& lo) {
    const unsigned u = __float_as_uint(x);
    hi = (short)(u >> 16);
    const float r = x - __uint_as_float(u & 0xffff0000u);
    lo = (short)(__float_as_uint(r) >> 16);
}

__device__ __forceinline__ u64 readlane_u64(u64 v, int src) {
    const unsigned lo = (unsigned)__builtin_amdgcn_readlane((int)(unsigned)v, src);
    const unsigned hi = (unsigned)__builtin_amdgcn_readlane((int)(unsigned)(v >> 32), src);
    return ((u64)hi << 32) | lo;
}

// ---------------- candidate table: (x,y,z,|p|^2) ----------------
__global__ __launch_bounds__(256) void prep_points(const float* __restrict__ pts,
                                                   float4* __restrict__ ctab) {
    const int e = blockIdx.x * 256 + threadIdx.x;     // 0..16383
    const float* __restrict__ p = pts + (size_t)e * 6;
    const float x = p[0], y = p[1], z = p[2];
    const float sq = x * x + y * y + z * z;
    ctab[e] = make_float4(x, y, z, sq);
}

// ---------------- weight transpose + hi/lo split, MFMA-fragment-packed ----------------
// layout per table: frag[(ks*8 + ct)*64 + lane][8]; lane holds B[k][col] with
// col=(lane&15)+16*ct, k=ks*32+(lane>>4)*8+j  -> wave loads are 1KB contiguous.
__global__ __launch_bounds__(256) void prep_weights(
    const float* __restrict__ Wc2, const float* __restrict__ Wn2,
    const float* __restrict__ Wo1, const float* __restrict__ Wo2,
    unsigned short* __restrict__ wbuf)
{
    const int e = blockIdx.x * 256 + threadIdx.x;   // 0..81919
    const float* src;
    unsigned short *dh, *dl;
    int idx;
    if (e < 16384)      { src = Wc2; dh = wbuf + WC_HI;  dl = wbuf + WC_LO;  idx = e; }
    else if (e < 32768) { src = Wn2; dh = wbuf + WN_HI;  dl = wbuf + WN_LO;  idx = e - 16384; }
    else if (e < 65536) { src = Wo1; dh = wbuf + WO1_HI; dl = wbuf + WO1_LO; idx = e - 32768; }
    else                { src = Wo2; dh = wbuf + WO2_HI; dl = wbuf + WO2_LO; idx = e - 65536; }
    const int j = idx & 7;
    const int l = (idx >> 3) & 63;
    const int tile = idx >> 9;
    const int ct = tile & 7;
    const int ks = tile >> 3;
    const int n = (l & 15) + 16 * ct;
    const int k = ks * 32 + ((l >> 4) << 3) + j;
    const float x = src[k * 128 + n];          // src is [K][128] row-major
    short hi, lo;
    bsplit(x, hi, lo);
    dh[idx] = (unsigned short)hi;
    dl[idx] = (unsigned short)lo;
}

// ---------------- KNN v4: one wave per query, cross-lane running top-16 ----------------
// Lanes 0..15 hold the current 16 smallest keys (ascending). Chunks of 64
// candidates; ballot-skip chunks that cannot improve; serial sorted-insert
// for the ~105 expected improving candidates. Exact (same u64 keys as before).
__global__ __launch_bounds__(256) void knn_kernel(const float4* __restrict__ ctab,
                                                  int* __restrict__ idx_out) {
    const int wq = blockIdx.x * 4 + (threadIdx.x >> 6);   // query id 0..16383
    const int b = wq >> 12;
    const int n = wq & (NPTS - 1);
    const int lane = threadIdx.x & 63;
    const float4* __restrict__ cb = ctab + (size_t)b * NPTS;

    const float4 q = cb[n];                    // qx,qy,qz,|q|^2

    u64 run = ~0ull;          // lanes 0..15: ascending top-16; others: don't-care
    u64 cur16max = ~0ull;     // wave-uniform copy of run[15]

    for (int c = 0; c < NPTS / 64; ++c) {
        const int m = lane + 64 * c;
        const float4 cc = cb[m];
        const float dot = q.x * cc.x + q.y * cc.y + q.z * cc.z;
        float d2 = (q.w + cc.w) - 2.0f * dot;  // bit-identical to passing version
        d2 = fmaxf(d2, 0.0f);
        u64 key = ((u64)__float_as_uint(d2) << 32) | (unsigned)m;
        if (m == n) key = ~0ull;               // exclude self

        u64 mask = __ballot(key < cur16max);
        while (mask) {
            const int src = (int)__builtin_ctzll(mask);
            const u64 K = readlane_u64(key, src);       // wave-uniform
            // sorted insert of K into run[0..15], dropping run[15]
            u64 prev = __shfl_up(run, 1, 64);
            if (lane == 0) prev = 0;                    // -inf sentinel
            run = (run < K) ? run : ((prev < K) ? K : prev);
            cur16max = readlane_u64(run, 15);
            mask &= mask - 1;                           // clear processed lane
            mask &= __ballot(key < cur16max);           // re-prune
        }
    }

    if (lane < KNBR)
        idx_out[((size_t)b * NPTS + n) * KNBR + lane] = (int)(run & 0xffffffffull);
}

// ---------------- branch compute: layer1 (VALU) + layer2 (MFMA) + k-max ----------------
template<int NIN>
__device__ __forceinline__ void branch_compute(
    const float (* __restrict__ inp)[4],           // 128 rows x 4 (LDS)
    const float* __restrict__ W1,                  // [NIN][128] fp32 global
    const float* __restrict__ b1,
    const float* __restrict__ b2,
    const unsigned short* __restrict__ w2hi,       // frag-packed [32 tiles][64][8]
    const unsigned short* __restrict__ w2lo,
    unsigned short (* __restrict__ catH)[264],
    unsigned short (* __restrict__ catL)[264],
    int colbase, int w, int l)
{
    const int lr = l & 15;
    const int lq = l >> 4;
    const int kb = lq * 8;

    f32x4 acc[2][8];
#pragma unroll
    for (int rt = 0; rt < 2; ++rt)
#pragma unroll
        for (int ct = 0; ct < 8; ++ct)
            acc[rt][ct] = (f32x4){0.f, 0.f, 0.f, 0.f};

    for (int ks = 0; ks < 4; ++ks) {
        const int c0 = ks * 32 + kb;
        // 1) issue ALL B-fragment loads (coalesced 1KB per wave-load)
        bf16x8 bh[8], bl[8];
        const unsigned short* fb = w2hi + ((size_t)(ks * 8) * 64 + l) * 8;
        const unsigned short* fq = w2lo + ((size_t)(ks * 8) * 64 + l) * 8;
#pragma unroll
        for (int ct = 0; ct < 8; ++ct) {
            bh[ct] = *(const bf16x8*)(fb + ct * 512);
            bl[ct] = *(const bf16x8*)(fq + ct * 512);
        }
        // 2) layer-1 + gelu + split (long VALU stretch hides the loads)
        float wr[NIN][8], bb[8];
#pragma unroll
        for (int d = 0; d < NIN; ++d) {
            *(float4*)&wr[d][0] = *(const float4*)(W1 + (d << 7) + c0);
            *(float4*)&wr[d][4] = *(const float4*)(W1 + (d << 7) + c0 + 4);
        }
        *(float4*)&bb[0] = *(const float4*)(b1 + c0);
        *(float4*)&bb[4] = *(const float4*)(b1 + c0 + 4);

        bf16x8 ah[2], al[2];
#pragma unroll
        for (int rt = 0; rt < 2; ++rt) {
            const int row = 32 * w + 16 * rt + lr;
            const float4 rv = *(const float4*)&inp[row][0];
#pragma unroll
            for (int jj = 0; jj < 8; ++jj) {
                float x = bb[jj] + rv.x * wr[0][jj] + rv.y * wr[1][jj] + rv.z * wr[2][jj];
                if (NIN == 4) x += rv.w * wr[3][jj];
                x = gelu_f(x);
                short hi, lo;
                bsplit(x, hi, lo);
                ah[rt][jj] = hi;
                al[rt][jj] = lo;
            }
        }
        // 3) MFMA cluster
#pragma unroll
        for (int ct = 0; ct < 8; ++ct) {
#pragma unroll
            for (int rt = 0; rt < 2; ++rt) {
                acc[rt][ct] = __builtin_amdgcn_mfma_f32_16x16x32_bf16(ah[rt], bh[ct], acc[rt][ct], 0, 0, 0);
                acc[rt][ct] = __builtin_amdgcn_mfma_f32_16x16x32_bf16(ah[rt], bl[ct], acc[rt][ct], 0, 0, 0);
                acc[rt][ct] = __builtin_amdgcn_mfma_f32_16x16x32_bf16(al[rt], bh[ct], acc[rt][ct], 0, 0, 0);
            }
        }
    }
    // k-max over 16 neighbors + bias + split to cat
#pragma unroll
    for (int rt = 0; rt < 2; ++rt) {
        const int p = 2 * w + rt;
#pragma unroll
        for (int ct = 0; ct < 8; ++ct) {
            const f32x4 a = acc[rt][ct];
            float m = fmaxf(fmaxf(a[0], a[1]), fmaxf(a[2], a[3]));
            m = fmaxf(m, __shfl_xor(m, 16));
            m = fmaxf(m, __shfl_xor(m, 32));
            const int col = lr + 16 * ct;
            const float v = m + b2[col];
            if (lq == 0) {
                short hi, lo;
                bsplit(v, hi, lo);
                catH[p][colbase + col] = (unsigned short)hi;
                catL[p][colbase + col] = (unsigned short)lo;
            }
        }
    }
}

// ---------------- fused MLP with MFMA: one block (256 thr) per 8 points ----------------
__global__ __launch_bounds__(256, 3) void mlp_mfma(
    const float* __restrict__ pts, const int* __restrict__ knn_idx,
    const float* __restrict__ Wc1, const float* __restrict__ bc1,
    const float* __restrict__ bc2,
    const float* __restrict__ Wn1, const float* __restrict__ bn1,
    const float* __restrict__ bn2,
    const float* __restrict__ bo1, const float* __restrict__ bo2,
    const unsigned short* __restrict__ wbuf,
    float* __restrict__ outp)
{
    __shared__ __align__(16) float rel[128][4];
    __shared__ __align__(16) float nin[128][4];
    __shared__ float qpt[8][6];
    __shared__ __align__(16) unsigned short catH[8][264];
    __shared__ __align__(16) unsigned short catL[8][264];
    __shared__ __align__(16) unsigned short o1H[8][136];
    __shared__ __align__(16) unsigned short o1L[8][136];

    const int t = threadIdx.x;
    const int w = t >> 6;
    const int l = t & 63;
    const int lr = l & 15;
    const int lq = l >> 4;
    const int kb = lq * 8;
    const int blk = blockIdx.x;
    const int b = blk >> 9;                 // 512 blocks per batch
    const int n0 = (blk & 511) * 8;
    const float* __restrict__ base = pts + (size_t)b * NPTS * 6;

    if (t < 48) qpt[t / 6][t % 6] = base[(size_t)(n0 + t / 6) * 6 + (t % 6)];
    __syncthreads();
    if (t < 128) {
        const int p = t >> 4;
        const int m = knn_idx[((size_t)b * NPTS + n0 + p) * KNBR + (t & 15)];
        const float cx = base[(size_t)m * 6 + 0];
        const float cy = base[(size_t)m * 6 + 1];
        const float cz = base[(size_t)m * 6 + 2];
        const float nx = base[(size_t)m * 6 + 3];
        const float ny = base[(size_t)m * 6 + 4];
        const float nz = base[(size_t)m * 6 + 5];
        rel[t][0] = cx - qpt[p][0];
        rel[t][1] = cy - qpt[p][1];
        rel[t][2] = cz - qpt[p][2];
        rel[t][3] = 0.0f;
        nin[t][0] = nx; nin[t][1] = ny; nin[t][2] = nz;
        nin[t][3] = 1.0f - (qpt[p][3] * nx + qpt[p][4] * ny + qpt[p][5] * nz);
    }
    __syncthreads();

    branch_compute<3>(rel, Wc1, bc1, bc2, wbuf + WC_HI, wbuf + WC_LO,
                      catH, catL, 0, w, l);
    branch_compute<4>(nin, Wn1, bn1, bn2, wbuf + WN_HI, wbuf + WN_LO,
                      catH, catL, 128, w, l);
    __syncthreads();

    // ---- output MLP layer 1: M=8 pts, wave w -> col tiles 2w, 2w+1; K=256 (8 ks)
    {
        f32x4 a1[2];
        a1[0] = (f32x4){0.f, 0.f, 0.f, 0.f};
        a1[1] = (f32x4){0.f, 0.f, 0.f, 0.f};
#pragma unroll
        for (int ks = 0; ks < 8; ++ks) {
            const int c0 = ks * 32 + kb;
            const bf16x8 ah = *(const bf16x8*)&catH[lr & 7][c0];
            const bf16x8 al = *(const bf16x8*)&catL[lr & 7][c0];
#pragma unroll
            for (int c2 = 0; c2 < 2; ++c2) {
                const int ct = 2 * w + c2;
                const unsigned short* wp = wbuf + WO1_HI + ((size_t)((ks * 8 + ct) * 64 + l)) * 8;
                const bf16x8 bh = *(const bf16x8*)wp;
                const bf16x8 bl = *(const bf16x8*)(wp + (WO1_LO - WO1_HI));
                a1[c2] = __builtin_amdgcn_mfma_f32_16x16x32_bf16(ah, bh, a1[c2], 0, 0, 0);
                a1[c2] = __builtin_amdgcn_mfma_f32_16x16x32_bf16(ah, bl, a1[c2], 0, 0, 0);
                a1[c2] = __builtin_amdgcn_mfma_f32_16x16x32_bf16(al, bh, a1[c2], 0, 0, 0);
            }
        }
#pragma unroll
        for (int c2 = 0; c2 < 2; ++c2) {
            const int col = lr + 16 * (2 * w + c2);
            const float bo = bo1[col];
#pragma unroll
            for (int r = 0; r < 4; ++r) {
                const int prow = lq * 4 + r;
                if (prow < 8) {
                    const float x = gelu_f(a1[c2][r] + bo);
                    short hi, lo;
                    bsplit(x, hi, lo);
                    o1H[prow][col] = (unsigned short)hi;
                    o1L[prow][col] = (unsigned short)lo;
                }
            }
        }
    }
    __syncthreads();
    // ---- output MLP layer 2: M=8, K=128 (4 ks)
    {
        f32x4 a2[2];
        a2[0] = (f32x4){0.f, 0.f, 0.f, 0.f};
        a2[1] = (f32x4){0.f, 0.f, 0.f, 0.f};
#pragma unroll
        for (int ks = 0; ks < 4; ++ks) {
            const int c0 = ks * 32 + kb;
            const bf16x8 ah = *(const bf16x8*)&o1H[lr & 7][c0];
            const bf16x8 al = *(const bf16x8*)&o1L[lr & 7][c0];
#pragma unroll
            for (int c2 = 0; c2 < 2; ++c2) {
                const int ct = 2 * w + c2;
                const unsigned short* wp = wbuf + WO2_HI + ((size_t)((ks * 8 + ct) * 64 + l)) * 8;
                const bf16x8 bh = *(const bf16x8*)wp;
                const bf16x8 bl = *(const bf16x8*)(wp + (WO2_LO - WO2_HI));
                a2[c2] = __builtin_amdgcn_mfma_f32_16x16x32_bf16(ah, bh, a2[c2], 0, 0, 0);
                a2[c2] = __builtin_amdgcn_mfma_f32_16x16x32_bf16(ah, bl, a2[c2], 0, 0, 0);
                a2[c2] = __builtin_amdgcn_mfma_f32_16x16x32_bf16(al, bh, a2[c2], 0, 0, 0);
            }
        }
#pragma unroll
        for (int c2 = 0; c2 < 2; ++c2) {
            const int col = lr + 16 * (2 * w + c2);
            const float bo = bo2[col];
#pragma unroll
            for (int r = 0; r < 4; ++r) {
                const int prow = lq * 4 + r;
                if (prow < 8)
                    outp[((size_t)b * NPTS + n0 + prow) * HDIM + col] = a2[c2][r] + bo;
            }
        }
    }
}

extern "C" void kernel_launch(void* const* d_in, const int* in_sizes, int n_in,
                              void* d_out, int out_size, void* d_ws, size_t ws_size,
                              hipStream_t stream) {
    const float* pts = (const float*)d_in[0];
    const float* Wc1 = (const float*)d_in[1];
    const float* bc1 = (const float*)d_in[2];
    const float* Wc2 = (const float*)d_in[3];
    const float* bc2 = (const float*)d_in[4];
    const float* Wn1 = (const float*)d_in[5];
    const float* bn1 = (const float*)d_in[6];
    const float* Wn2 = (const float*)d_in[7];
    const float* bn2 = (const float*)d_in[8];
    const float* Wo1 = (const float*)d_in[9];
    const float* bo1 = (const float*)d_in[10];
    const float* Wo2 = (const float*)d_in[11];
    const float* bo2 = (const float*)d_in[12];
    float* outp = (float*)d_out;
    int* idx = (int*)d_ws;
    float4* ctab = (float4*)((char*)d_ws + WSOFF_W);            // phase A
    unsigned short* wbuf = (unsigned short*)((char*)d_ws + WSOFF_W);  // phase B (after knn)

    prep_points<<<dim3(BATCH * NPTS / 256), dim3(256), 0, stream>>>(pts, ctab);
    knn_kernel<<<dim3(BATCH * NPTS / 4), dim3(256), 0, stream>>>(ctab, idx);
    prep_weights<<<dim3(320), dim3(256), 0, stream>>>(Wc2, Wn2, Wo1, Wo2, wbuf);
    mlp_mfma<<<dim3(BATCH * NPTS / 8), dim3(256), 0, stream>>>(
        pts, idx, Wc1, bc1, bc2, Wn1, bn1, bn2, bo1, bo2, wbuf, outp);
}